// Round 7
// baseline (617.440 us; speedup 1.0000x reference)
//
#include <hip/hip_runtime.h>

#define N_NODES 100000
#define N_EDGES 1600000
#define DIM     128
#define OUTD    16
#define SCAN_CHUNK 1024
#define NB ((N_NODES + SCAN_CHUNK - 1) / SCAN_CHUNK)   // 98

typedef unsigned int  uint;
typedef unsigned short ushort;
typedef __attribute__((ext_vector_type(8))) short short8;   // 8 bf16 (4 VGPRs)
typedef __attribute__((ext_vector_type(4))) float f32x4;    // MFMA C/D
typedef __attribute__((ext_vector_type(4))) int   i32x4;    // clang vector (nt ok)
typedef __attribute__((ext_vector_type(4))) uint  u32x4;

__device__ __forceinline__ ushort f2bf(float f) {           // RNE fp32->bf16
    uint u = __float_as_uint(f);
    u = u + 0x7fffu + ((u >> 16) & 1u);
    return (ushort)(u >> 16);
}
__device__ __forceinline__ float bflo(uint v) { return __uint_as_float(v << 16); }
__device__ __forceinline__ float bfhi(uint v) { return __uint_as_float(v & 0xffff0000u); }

// physical XCD id of the executing wave (gfx940+: HW_REG_XCC_ID = 20)
__device__ __forceinline__ int get_xcd() {
    return (int)(__builtin_amdgcn_s_getreg(20 | (31 << 11)) & 7);
}

#define SLICES 8
#define RPS (N_NODES / SLICES)   // 12500 rows/slice -> 50 KB deg / ~800 KB csr window
#define CHUNK4 1024              // int4s per ticket chunk (4096 edges)
#define NCH ((N_EDGES / 4 + CHUNK4 - 1) / CHUNK4)   // 391 chunks per slice

// ---------------- degree count: XCD-affine slices + ticket stealing ----------------
__global__ __launch_bounds__(256) void k_count(const int* __restrict__ row,
                                               int* __restrict__ deg,
                                               int* __restrict__ ticket) {
    __shared__ int sh_t;
    int xcd = get_xcd();
    const i32x4* row4 = (const i32x4*)row;
    for (int ss = 0; ss < SLICES; ++ss) {
        int slice = (xcd + ss) & (SLICES - 1);   // own slice first, then steal
        int lo = slice * RPS, hi = lo + RPS;
        for (;;) {
            __syncthreads();
            if (threadIdx.x == 0) sh_t = atomicAdd(&ticket[slice], 1);
            __syncthreads();
            int t = sh_t;
            if (t >= NCH) break;
            int base = t * CHUNK4 + threadIdx.x;
#pragma unroll
            for (int i = 0; i < CHUNK4 / 256; ++i) {
                int idx = base + i * 256;
                if (idx < N_EDGES / 4) {
                    i32x4 r = __builtin_nontemporal_load(row4 + idx);
                    if (r.x >= lo && r.x < hi) atomicAdd(&deg[r.x], 1);
                    if (r.y >= lo && r.y < hi) atomicAdd(&deg[r.y], 1);
                    if (r.z >= lo && r.z < hi) atomicAdd(&deg[r.z], 1);
                    if (r.w >= lo && r.w < hi) atomicAdd(&deg[r.w], 1);
                }
            }
        }
    }
}

// ---------------- pure streaming conversions: x->bf16, W transposes ----------------
__global__ __launch_bounds__(256) void k_convert(
        const float4* __restrict__ x4,
        const float* __restrict__ We, const float* __restrict__ W1,
        const float* __restrict__ W2, const float* __restrict__ Wc,
        ushort* __restrict__ xb, ushort* __restrict__ Wt, ushort* __restrict__ Wct) {
    int tid = blockIdx.x * blockDim.x + threadIdx.x;
    int stride = gridDim.x * blockDim.x;
    for (int i = tid; i < N_NODES * DIM / 4; i += stride) {
        float4 v = x4[i];
        ushort4 r;
        r.x = f2bf(v.x); r.y = f2bf(v.y); r.z = f2bf(v.z); r.w = f2bf(v.w);
        *(ushort4*)(xb + (size_t)i * 4) = r;
    }
    for (int i = tid; i < 3 * DIM * DIM; i += stride) {   // Wt[br][n][k] = W[br][k][n]
        int b = i >> 14, r2 = i & (DIM * DIM - 1);
        int k = r2 >> 7, n = r2 & 127;
        const float* W = (b == 0) ? We : (b == 1) ? W1 : W2;
        Wt[b * DIM * DIM + n * DIM + k] = f2bf(W[r2]);
    }
    for (int i = tid; i < 384 * OUTD; i += stride) {      // Wct[o][k] = Wc[k][o]
        int k = i >> 4, o = i & 15;
        Wct[o * 384 + k] = f2bf(Wc[i]);
    }
}

// ---------------- scans (build CSR offsets) ----------------
__global__ void k_scan1(const int* __restrict__ deg, int* __restrict__ bsum) {
    __shared__ int sd[256];
    int t = threadIdx.x;
    int base = blockIdx.x * SCAN_CHUNK + t * 4;
    int s = 0;
#pragma unroll
    for (int j = 0; j < 4; ++j) { int i = base + j; if (i < N_NODES) s += deg[i]; }
    sd[t] = s;
    __syncthreads();
    for (int off = 128; off > 0; off >>= 1) {
        if (t < off) sd[t] += sd[t + off];
        __syncthreads();
    }
    if (t == 0) bsum[blockIdx.x] = sd[0];
}

__global__ void k_scan2(const int* __restrict__ bsum, int* __restrict__ boff,
                        int* __restrict__ offsets) {
    __shared__ int s[128];
    int t = threadIdx.x;
    int v = (t < NB) ? bsum[t] : 0;
    s[t] = v;
    __syncthreads();
    for (int off = 1; off < 128; off <<= 1) {
        int a = (t >= off) ? s[t - off] : 0;
        __syncthreads();
        s[t] += a;
        __syncthreads();
    }
    if (t < NB) boff[t] = s[t] - v;
    if (t == NB - 1) offsets[N_NODES] = s[t];
}

__global__ void k_scan3(const int* __restrict__ deg, const int* __restrict__ boff,
                        int* __restrict__ offsets, int* __restrict__ cursor) {
    __shared__ int sd[256];
    int t = threadIdx.x;
    int base = blockIdx.x * SCAN_CHUNK + t * 4;
    int d[4];
    int s = 0;
#pragma unroll
    for (int j = 0; j < 4; ++j) {
        int i = base + j;
        d[j] = (i < N_NODES) ? deg[i] : 0;
        s += d[j];
    }
    sd[t] = s;
    __syncthreads();
    for (int off = 1; off < 256; off <<= 1) {
        int add = (t >= off) ? sd[t - off] : 0;
        __syncthreads();
        sd[t] += add;
        __syncthreads();
    }
    int run = boff[blockIdx.x] + (sd[t] - s);
#pragma unroll
    for (int j = 0; j < 4; ++j) {
        int i = base + j;
        if (i < N_NODES) { offsets[i] = run; cursor[i] = run; run += d[j]; }
    }
}

// ---------------- scatter: XCD-affine slices + ticket stealing ----------------
// All plain csr_col stores for a slice originate on one XCD -> full-line writebacks
__global__ __launch_bounds__(256) void k_scatter(const int* __restrict__ row,
                                                 const int* __restrict__ col,
                                                 int* __restrict__ cursor,
                                                 int* __restrict__ csr_col,
                                                 int* __restrict__ ticket) {
    __shared__ int sh_t;
    int xcd = get_xcd();
    const i32x4* row4 = (const i32x4*)row;
    const i32x4* col4 = (const i32x4*)col;
    for (int ss = 0; ss < SLICES; ++ss) {
        int slice = (xcd + ss) & (SLICES - 1);
        int lo = slice * RPS, hi = lo + RPS;
        for (;;) {
            __syncthreads();
            if (threadIdx.x == 0) sh_t = atomicAdd(&ticket[slice], 1);
            __syncthreads();
            int t = sh_t;
            if (t >= NCH) break;
            int base = t * CHUNK4 + threadIdx.x;
#pragma unroll
            for (int i = 0; i < CHUNK4 / 256; ++i) {
                int idx = base + i * 256;
                if (idx < N_EDGES / 4) {
                    i32x4 r = __builtin_nontemporal_load(row4 + idx);
                    i32x4 c = __builtin_nontemporal_load(col4 + idx);
                    if (r.x >= lo && r.x < hi) { int p = atomicAdd(&cursor[r.x], 1); csr_col[p] = c.x; }
                    if (r.y >= lo && r.y < hi) { int p = atomicAdd(&cursor[r.y], 1); csr_col[p] = c.y; }
                    if (r.z >= lo && r.z < hi) { int p = atomicAdd(&cursor[r.z], 1); csr_col[p] = c.z; }
                    if (r.w >= lo && r.w < hi) { int p = atomicAdd(&cursor[r.w], 1); csr_col[p] = c.w; }
                }
            }
        }
    }
}

// ---------------- SpMM: quarter-wave 16B gathers, raw sums ----------------
// lanes [16q..16q+15] handle edge j+q; each lane loads 16 B (8 bf16 features);
// cross-quarter reduce via shfl_xor(16/32) at the end.
__global__ __launch_bounds__(256) void k_spmm(const ushort* __restrict__ in,
                                              ushort* __restrict__ outp,
                                              const int* __restrict__ offsets,
                                              const int* __restrict__ csr_col) {
    int wid = threadIdx.x >> 6, lane = threadIdx.x & 63;
    int sub = lane >> 4, sl = lane & 15;
    int node = blockIdx.x * 4 + wid;
    int start = __builtin_amdgcn_readfirstlane(offsets[node]);
    int end   = __builtin_amdgcn_readfirstlane(offsets[node + 1]);
    float f0 = 0.f, f1 = 0.f, f2 = 0.f, f3 = 0.f;
    float f4 = 0.f, f5 = 0.f, f6 = 0.f, f7 = 0.f;
    int j = start;
    for (; j + 8 <= end; j += 8) {
        int cA = csr_col[j + sub];
        int cB = csr_col[j + 4 + sub];
        u32x4 a = *(const u32x4*)(in + ((size_t)cA << 7) + sl * 8);
        u32x4 b = *(const u32x4*)(in + ((size_t)cB << 7) + sl * 8);
        f0 += bflo(a.x) + bflo(b.x); f1 += bfhi(a.x) + bfhi(b.x);
        f2 += bflo(a.y) + bflo(b.y); f3 += bfhi(a.y) + bfhi(b.y);
        f4 += bflo(a.z) + bflo(b.z); f5 += bfhi(a.z) + bfhi(b.z);
        f6 += bflo(a.w) + bflo(b.w); f7 += bfhi(a.w) + bfhi(b.w);
    }
    for (; j < end; j += 4) {
        if (j + sub < end) {
            int c = csr_col[j + sub];
            u32x4 a = *(const u32x4*)(in + ((size_t)c << 7) + sl * 8);
            f0 += bflo(a.x); f1 += bfhi(a.x);
            f2 += bflo(a.y); f3 += bfhi(a.y);
            f4 += bflo(a.z); f5 += bfhi(a.z);
            f6 += bflo(a.w); f7 += bfhi(a.w);
        }
    }
    f0 += __shfl_xor(f0, 16, 64); f0 += __shfl_xor(f0, 32, 64);
    f1 += __shfl_xor(f1, 16, 64); f1 += __shfl_xor(f1, 32, 64);
    f2 += __shfl_xor(f2, 16, 64); f2 += __shfl_xor(f2, 32, 64);
    f3 += __shfl_xor(f3, 16, 64); f3 += __shfl_xor(f3, 32, 64);
    f4 += __shfl_xor(f4, 16, 64); f4 += __shfl_xor(f4, 32, 64);
    f5 += __shfl_xor(f5, 16, 64); f5 += __shfl_xor(f5, 32, 64);
    f6 += __shfl_xor(f6, 16, 64); f6 += __shfl_xor(f6, 32, 64);
    f7 += __shfl_xor(f7, 16, 64); f7 += __shfl_xor(f7, 32, 64);
    if (sub == 0) {
        uint o0 = (uint)f2bf(f0) | ((uint)f2bf(f1) << 16);
        uint o1 = (uint)f2bf(f2) | ((uint)f2bf(f3) << 16);
        uint o2 = (uint)f2bf(f4) | ((uint)f2bf(f5) << 16);
        uint o3 = (uint)f2bf(f6) | ((uint)f2bf(f7) << 16);
        u32x4 ov = {o0, o1, o2, o3};
        __builtin_nontemporal_store(ov, (u32x4*)(outp + ((size_t)node << 7) + sl * 8));
    }
}

// ---------------- fused MFMA GEMM x3 (+row-scale norm) + relu + classifier ---------
#define XSS (DIM + 8)   // 136 bf16 = 272B row stride

__global__ __launch_bounds__(256) void k_fused(
        const ushort* __restrict__ xb, const ushort* __restrict__ y1r,
        const ushort* __restrict__ y2r, const int* __restrict__ deg,
        const ushort* __restrict__ Wt, const ushort* __restrict__ Wct,
        const float* __restrict__ b_ego, const float* __restrict__ b_h1,
        const float* __restrict__ b_h2, const float* __restrict__ b_cls,
        float* __restrict__ out) {
    __shared__ __align__(16) ushort Xs[32 * XSS];
    __shared__ __align__(16) ushort Hs[32 * XSS];

    int t = threadIdx.x;
    int lane = t & 63, w = t >> 6;
    int q = lane >> 4, l = lane & 15;
    int node0 = blockIdx.x * 32;

    float dvv[2][4];
#pragma unroll
    for (int mt = 0; mt < 2; ++mt) {
        int4 dg = *(const int4*)(deg + node0 + mt * 16 + q * 4);
        dvv[mt][0] = 1.f / (float)max(dg.x, 1);
        dvv[mt][1] = 1.f / (float)max(dg.y, 1);
        dvv[mt][2] = 1.f / (float)max(dg.z, 1);
        dvv[mt][3] = 1.f / (float)max(dg.w, 1);
    }

    f32x4 cout0 = {0.f, 0.f, 0.f, 0.f}, cout1 = {0.f, 0.f, 0.f, 0.f};

    for (int br = 0; br < 3; ++br) {
        const ushort* src = (br == 0) ? xb : (br == 1) ? y1r : y2r;
        const ushort* Wtb = Wt + br * DIM * DIM;
        const float* bias = (br == 0) ? b_ego : (br == 1) ? b_h1 : b_h2;

        __syncthreads();
        {   // stage 32x128 bf16 tile (pure copy)
            int row = t >> 3, col = (t & 7) * 16;
            const ushort* sp = src + ((size_t)(node0 + row) << 7) + col;
            uint4 u0 = *(const uint4*)sp;
            uint4 u1 = *(const uint4*)(sp + 8);
            *(uint4*)(Xs + row * XSS + col) = u0;
            *(uint4*)(Xs + row * XSS + col + 8) = u1;
        }
        __syncthreads();

        short8 afr[2][4];
#pragma unroll
        for (int mt = 0; mt < 2; ++mt)
#pragma unroll
            for (int ks = 0; ks < 4; ++ks)
                afr[mt][ks] = *(const short8*)(Xs + (mt * 16 + l) * XSS + ks * 32 + q * 8);
        short8 bfr[2][4];
#pragma unroll
        for (int nt = 0; nt < 2; ++nt)
#pragma unroll
            for (int ks = 0; ks < 4; ++ks)
                bfr[nt][ks] = *(const short8*)(Wtb + (size_t)(w * 32 + nt * 16 + l) * DIM + ks * 32 + q * 8);

        f32x4 hc[2][2];
        hc[0][0] = hc[0][1] = hc[1][0] = hc[1][1] = (f32x4){0.f, 0.f, 0.f, 0.f};
#pragma unroll
        for (int ks = 0; ks < 4; ++ks)
#pragma unroll
            for (int mt = 0; mt < 2; ++mt)
#pragma unroll
                for (int nt = 0; nt < 2; ++nt)
                    hc[mt][nt] = __builtin_amdgcn_mfma_f32_16x16x32_bf16(
                        afr[mt][ks], bfr[nt][ks], hc[mt][nt], 0, 0, 0);

#pragma unroll
        for (int nt = 0; nt < 2; ++nt) {
            float bv = bias[w * 32 + nt * 16 + l];
#pragma unroll
            for (int mt = 0; mt < 2; ++mt)
#pragma unroll
                for (int r = 0; r < 4; ++r) {
                    float s = (br == 0) ? 1.f
                            : (br == 1) ? dvv[mt][r]
                                        : dvv[mt][r] * dvv[mt][r];
                    float v = hc[mt][nt][r] * s + bv;
                    v = v > 0.f ? v : 0.f;
                    Hs[(mt * 16 + q * 4 + r) * XSS + w * 32 + nt * 16 + l] = f2bf(v);
                }
        }
        __syncthreads();

        short8 ha0 = *(const short8*)(Hs + l * XSS + w * 32 + q * 8);
        short8 ha1 = *(const short8*)(Hs + (16 + l) * XSS + w * 32 + q * 8);
        short8 wc  = *(const short8*)(Wct + (size_t)l * 384 + br * DIM + w * 32 + q * 8);
        cout0 = __builtin_amdgcn_mfma_f32_16x16x32_bf16(ha0, wc, cout0, 0, 0, 0);
        cout1 = __builtin_amdgcn_mfma_f32_16x16x32_bf16(ha1, wc, cout1, 0, 0, 0);
    }

    float* red = (float*)Xs;
#pragma unroll
    for (int r = 0; r < 4; ++r) {
        red[w * 512 + (q * 4 + r) * 16 + l]      = cout0[r];
        red[w * 512 + (16 + q * 4 + r) * 16 + l] = cout1[r];
    }
    __syncthreads();
#pragma unroll
    for (int p = t; p < 512; p += 256) {
        float s = red[p] + red[512 + p] + red[1024 + p] + red[1536 + p];
        out[(size_t)node0 * OUTD + p] = s + b_cls[p & 15];
    }
}

// ---------------- launcher ----------------
static inline size_t align256(size_t v) { return (v + 255) & ~(size_t)255; }

extern "C" void kernel_launch(void* const* d_in, const int* in_sizes, int n_in,
                              void* d_out, int out_size, void* d_ws, size_t ws_size,
                              hipStream_t stream) {
    const float* x      = (const float*)d_in[0];
    const int*   ei     = (const int*)d_in[1];
    const float* W_ego  = (const float*)d_in[2];
    const float* b_ego  = (const float*)d_in[3];
    const float* W_h1   = (const float*)d_in[4];
    const float* b_h1   = (const float*)d_in[5];
    const float* W_h2   = (const float*)d_in[6];
    const float* b_h2   = (const float*)d_in[7];
    const float* W_cls  = (const float*)d_in[8];
    const float* b_cls  = (const float*)d_in[9];
    float* out = (float*)d_out;

    const int* row = ei;
    const int* col = ei + N_EDGES;

    char* p = (char*)d_ws;
    int* deg      = (int*)p;    p += align256((size_t)N_NODES * 4);       // +128B spare
    int* tcount   = deg + N_NODES;        // 8 ints, inside deg's aligned block
    int* tscat    = deg + N_NODES + 8;    // 8 ints
    int* offsets  = (int*)p;    p += align256((size_t)(N_NODES + 1) * 4);
    int* cursor   = (int*)p;    p += align256((size_t)N_NODES * 4);
    int* bsum     = (int*)p;    p += align256((size_t)NB * 4);
    int* boff     = (int*)p;    p += align256((size_t)NB * 4);
    int* csr_col  = (int*)p;    p += align256((size_t)N_EDGES * 4);
    ushort* xb    = (ushort*)p; p += align256((size_t)N_NODES * DIM * 2);
    ushort* y1r   = (ushort*)p; p += align256((size_t)N_NODES * DIM * 2);
    ushort* y2r   = (ushort*)p; p += align256((size_t)N_NODES * DIM * 2);
    ushort* Wt    = (ushort*)p; p += align256((size_t)3 * DIM * DIM * 2);
    ushort* Wct   = (ushort*)p; p += align256((size_t)384 * OUTD * 2);

    // zero deg + both ticket arrays (they live in deg's aligned block)
    (void)hipMemsetAsync(deg, 0, align256((size_t)N_NODES * 4), stream);

    k_count<<<1024, 256, 0, stream>>>(row, deg, tcount);
    k_convert<<<2048, 256, 0, stream>>>((const float4*)x, W_ego, W_h1, W_h2, W_cls,
                                        xb, Wt, Wct);
    k_scan1<<<NB, 256, 0, stream>>>(deg, bsum);
    k_scan2<<<1, 128, 0, stream>>>(bsum, boff, offsets);
    k_scan3<<<NB, 256, 0, stream>>>(deg, boff, offsets, cursor);
    k_scatter<<<1024, 256, 0, stream>>>(row, col, cursor, csr_col, tscat);

    k_spmm<<<N_NODES / 4, 256, 0, stream>>>(xb,  y1r, offsets, csr_col);
    k_spmm<<<N_NODES / 4, 256, 0, stream>>>(y1r, y2r, offsets, csr_col);

    k_fused<<<N_NODES / 32, 256, 0, stream>>>(xb, y1r, y2r, deg, Wt, Wct,
                                              b_ego, b_h1, b_h2, b_cls, out);
}

// Round 8
// 381.134 us; speedup vs baseline: 1.6200x; 1.6200x over previous
//
#include <hip/hip_runtime.h>

#define N_NODES 100000
#define N_EDGES 1600000
#define DIM     128
#define OUTD    16

typedef unsigned int  uint;
typedef unsigned short ushort;
typedef __attribute__((ext_vector_type(8))) short short8;   // 8 bf16 (4 VGPRs)
typedef __attribute__((ext_vector_type(4))) float f32x4;    // MFMA C/D
typedef __attribute__((ext_vector_type(4))) int   i32x4;    // clang vector (nt ok)
typedef __attribute__((ext_vector_type(4))) uint  u32x4;

__device__ __forceinline__ ushort f2bf(float f) {           // RNE fp32->bf16
    uint u = __float_as_uint(f);
    u = u + 0x7fffu + ((u >> 16) & 1u);
    return (ushort)(u >> 16);
}
__device__ __forceinline__ float bflo(uint v) { return __uint_as_float(v << 16); }
__device__ __forceinline__ float bfhi(uint v) { return __uint_as_float(v & 0xffff0000u); }

// ---- bucket decomposition: bucket = row >> 9 (512 rows per bucket) ----
#define RPB    512
#define NBUCK  196                    // ceil(100000/512)
#define NBLK   500                    // hist/place blocks
#define CHUNK4 800                    // int4s per block chunk (3200 edges); 500*800 = 400000 = E/4
#define BCAP   10240                  // k_build LDS staging capacity (mean bucket ~8192, 22 sigma margin)

// ---------------- pass 1: per-(block,bucket) histogram, LDS only ----------------
__global__ __launch_bounds__(256) void k_hist(const int* __restrict__ row,
                                              int* __restrict__ hist) {
    __shared__ int h[NBUCK];
    for (int i = threadIdx.x; i < NBUCK; i += 256) h[i] = 0;
    __syncthreads();
    const i32x4* row4 = (const i32x4*)row;
    int base = blockIdx.x * CHUNK4;
    for (int i = threadIdx.x; i < CHUNK4; i += 256) {
        i32x4 r = __builtin_nontemporal_load(row4 + base + i);
        atomicAdd(&h[r.x >> 9], 1);
        atomicAdd(&h[r.y >> 9], 1);
        atomicAdd(&h[r.z >> 9], 1);
        atomicAdd(&h[r.w >> 9], 1);
    }
    __syncthreads();
    for (int i = threadIdx.x; i < NBUCK; i += 256)
        hist[blockIdx.x * NBUCK + i] = h[i];   // block-major: coalesced here & in scan
}

// ---------------- pass 2: scan -> exact start slot per (block,bucket) -------------
// hist[k][b] becomes start[k][b]; bucket_base = CSR base per bucket
__global__ void k_scanh(int* __restrict__ hist, int* __restrict__ bucket_base,
                        int* __restrict__ offsets) {
    __shared__ int tot[256];
    int b = threadIdx.x;
    int s = 0;
    if (b < NBUCK) {
#pragma unroll 8
        for (int k = 0; k < NBLK; ++k) {       // column scan, coalesced across threads
            int v = hist[k * NBUCK + b];
            hist[k * NBUCK + b] = s;
            s += v;
        }
    }
    tot[b] = (b < NBUCK) ? s : 0;
    __syncthreads();
    for (int off = 1; off < 256; off <<= 1) {  // Hillis-Steele inclusive
        int a = (b >= off) ? tot[b - off] : 0;
        __syncthreads();
        tot[b] += a;
        __syncthreads();
    }
    int base = tot[b] - s;                     // exclusive prefix
    if (b < NBUCK) {
        bucket_base[b] = base;
#pragma unroll 8
        for (int k = 0; k < NBLK; ++k) hist[k * NBUCK + b] += base;
    }
    if (b == NBUCK - 1) {
        bucket_base[NBUCK] = base + s;
        offsets[N_NODES]   = base + s;         // == N_EDGES
    }
}

// ---------------- pass 3: place packed (localrow,col) into bucket runs ------------
// runs are contiguous per (block,bucket): only run-boundary lines shared (<=2 writers)
__global__ __launch_bounds__(256) void k_place(const int* __restrict__ row,
                                               const int* __restrict__ col,
                                               const int* __restrict__ start,
                                               uint* __restrict__ packed) {
    __shared__ int cur[NBUCK];
    for (int i = threadIdx.x; i < NBUCK; i += 256)
        cur[i] = start[blockIdx.x * NBUCK + i];
    __syncthreads();
    const i32x4* row4 = (const i32x4*)row;
    const i32x4* col4 = (const i32x4*)col;
    int base = blockIdx.x * CHUNK4;
    for (int i = threadIdx.x; i < CHUNK4; i += 256) {
        i32x4 r = __builtin_nontemporal_load(row4 + base + i);
        i32x4 c = __builtin_nontemporal_load(col4 + base + i);
        int p;
        p = atomicAdd(&cur[r.x >> 9], 1); packed[p] = ((uint)(r.x & 511) << 17) | (uint)c.x;
        p = atomicAdd(&cur[r.y >> 9], 1); packed[p] = ((uint)(r.y & 511) << 17) | (uint)c.y;
        p = atomicAdd(&cur[r.z >> 9], 1); packed[p] = ((uint)(r.z & 511) << 17) | (uint)c.z;
        p = atomicAdd(&cur[r.w >> 9], 1); packed[p] = ((uint)(r.w & 511) << 17) | (uint)c.w;
    }
}

// ---------------- pass 4: per-bucket CSR build, one WG per bucket -----------------
// deg + offsets streamed out; csr_col scatter confined to ~32KB window on ONE CU
__global__ __launch_bounds__(256) void k_build(const uint* __restrict__ packed,
                                               const int* __restrict__ bucket_base,
                                               int* __restrict__ deg,
                                               int* __restrict__ offsets,
                                               int* __restrict__ csr_col) {
    __shared__ uint stage[BCAP];               // 40 KB
    __shared__ int hist[RPB];                  // 2 KB
    __shared__ int loff[RPB];                  // 2 KB (offsets, then cursor)
    __shared__ int psum[256];
    int t = threadIdx.x;
    int b = blockIdx.x;
    int base = bucket_base[b];
    int n    = bucket_base[b + 1] - base;
    int lo   = b * RPB;
    bool lds_ok = (n <= BCAP);

    for (int i = t; i < RPB; i += 256) hist[i] = 0;
    __syncthreads();
    if (lds_ok) {
        for (int i = t; i < n; i += 256) {
            uint pk = packed[base + i];
            stage[i] = pk;
            atomicAdd(&hist[pk >> 17], 1);
        }
    } else {
        for (int i = t; i < n; i += 256) atomicAdd(&hist[packed[base + i] >> 17], 1);
    }
    __syncthreads();

    // exclusive scan of hist[0..511] -> loff
    int a0 = hist[2 * t], a1 = hist[2 * t + 1];
    psum[t] = a0 + a1;
    __syncthreads();
    for (int off = 1; off < 256; off <<= 1) {
        int a = (t >= off) ? psum[t - off] : 0;
        __syncthreads();
        psum[t] += a;
        __syncthreads();
    }
    int excl = psum[t] - (a0 + a1);
    loff[2 * t]     = excl;
    loff[2 * t + 1] = excl + a0;
    __syncthreads();

    // stream out deg + offsets (coalesced)
    for (int i = t; i < RPB; i += 256) {
        int node = lo + i;
        if (node < N_NODES) {
            deg[node]     = hist[i];
            offsets[node] = base + loff[i];
        }
    }
    __syncthreads();

    // in-bucket scatter; loff doubles as cursor (LDS atomics)
    if (lds_ok) {
        for (int i = t; i < n; i += 256) {
            uint pk = stage[i];
            int p = atomicAdd(&loff[pk >> 17], 1);
            csr_col[base + p] = (int)(pk & 0x1FFFFu);
        }
    } else {
        for (int i = t; i < n; i += 256) {
            uint pk = packed[base + i];
            int p = atomicAdd(&loff[pk >> 17], 1);
            csr_col[base + p] = (int)(pk & 0x1FFFFu);
        }
    }
}

// ---------------- streaming conversions: x->bf16, W transposes ----------------
__global__ __launch_bounds__(256) void k_convert(
        const float4* __restrict__ x4,
        const float* __restrict__ We, const float* __restrict__ W1,
        const float* __restrict__ W2, const float* __restrict__ Wc,
        ushort* __restrict__ xb, ushort* __restrict__ Wt, ushort* __restrict__ Wct) {
    int tid = blockIdx.x * blockDim.x + threadIdx.x;
    int stride = gridDim.x * blockDim.x;
    for (int i = tid; i < N_NODES * DIM / 4; i += stride) {
        float4 v = x4[i];
        ushort4 r;
        r.x = f2bf(v.x); r.y = f2bf(v.y); r.z = f2bf(v.z); r.w = f2bf(v.w);
        *(ushort4*)(xb + (size_t)i * 4) = r;
    }
    for (int i = tid; i < 3 * DIM * DIM; i += stride) {   // Wt[br][n][k] = W[br][k][n]
        int b = i >> 14, r2 = i & (DIM * DIM - 1);
        int k = r2 >> 7, n = r2 & 127;
        const float* W = (b == 0) ? We : (b == 1) ? W1 : W2;
        Wt[b * DIM * DIM + n * DIM + k] = f2bf(W[r2]);
    }
    for (int i = tid; i < 384 * OUTD; i += stride) {      // Wct[o][k] = Wc[k][o]
        int k = i >> 4, o = i & 15;
        Wct[o * 384 + k] = f2bf(Wc[i]);
    }
}

// ---------------- SpMM: quarter-wave 16B gathers, raw sums ----------------
__global__ __launch_bounds__(256) void k_spmm(const ushort* __restrict__ in,
                                              ushort* __restrict__ outp,
                                              const int* __restrict__ offsets,
                                              const int* __restrict__ csr_col) {
    int wid = threadIdx.x >> 6, lane = threadIdx.x & 63;
    int sub = lane >> 4, sl = lane & 15;
    int node = blockIdx.x * 4 + wid;
    int start = __builtin_amdgcn_readfirstlane(offsets[node]);
    int end   = __builtin_amdgcn_readfirstlane(offsets[node + 1]);
    float f0 = 0.f, f1 = 0.f, f2 = 0.f, f3 = 0.f;
    float f4 = 0.f, f5 = 0.f, f6 = 0.f, f7 = 0.f;
    int j = start;
    for (; j + 8 <= end; j += 8) {
        int cA = csr_col[j + sub];
        int cB = csr_col[j + 4 + sub];
        u32x4 a = *(const u32x4*)(in + ((size_t)cA << 7) + sl * 8);
        u32x4 b = *(const u32x4*)(in + ((size_t)cB << 7) + sl * 8);
        f0 += bflo(a.x) + bflo(b.x); f1 += bfhi(a.x) + bfhi(b.x);
        f2 += bflo(a.y) + bflo(b.y); f3 += bfhi(a.y) + bfhi(b.y);
        f4 += bflo(a.z) + bflo(b.z); f5 += bfhi(a.z) + bfhi(b.z);
        f6 += bflo(a.w) + bflo(b.w); f7 += bfhi(a.w) + bfhi(b.w);
    }
    for (; j < end; j += 4) {
        if (j + sub < end) {
            int c = csr_col[j + sub];
            u32x4 a = *(const u32x4*)(in + ((size_t)c << 7) + sl * 8);
            f0 += bflo(a.x); f1 += bfhi(a.x);
            f2 += bflo(a.y); f3 += bfhi(a.y);
            f4 += bflo(a.z); f5 += bfhi(a.z);
            f6 += bflo(a.w); f7 += bfhi(a.w);
        }
    }
    f0 += __shfl_xor(f0, 16, 64); f0 += __shfl_xor(f0, 32, 64);
    f1 += __shfl_xor(f1, 16, 64); f1 += __shfl_xor(f1, 32, 64);
    f2 += __shfl_xor(f2, 16, 64); f2 += __shfl_xor(f2, 32, 64);
    f3 += __shfl_xor(f3, 16, 64); f3 += __shfl_xor(f3, 32, 64);
    f4 += __shfl_xor(f4, 16, 64); f4 += __shfl_xor(f4, 32, 64);
    f5 += __shfl_xor(f5, 16, 64); f5 += __shfl_xor(f5, 32, 64);
    f6 += __shfl_xor(f6, 16, 64); f6 += __shfl_xor(f6, 32, 64);
    f7 += __shfl_xor(f7, 16, 64); f7 += __shfl_xor(f7, 32, 64);
    if (sub == 0) {
        uint o0 = (uint)f2bf(f0) | ((uint)f2bf(f1) << 16);
        uint o1 = (uint)f2bf(f2) | ((uint)f2bf(f3) << 16);
        uint o2 = (uint)f2bf(f4) | ((uint)f2bf(f5) << 16);
        uint o3 = (uint)f2bf(f6) | ((uint)f2bf(f7) << 16);
        u32x4 ov = {o0, o1, o2, o3};
        __builtin_nontemporal_store(ov, (u32x4*)(outp + ((size_t)node << 7) + sl * 8));
    }
}

// ---------------- fused MFMA GEMM x3 (+row-scale norm) + relu + classifier ---------
#define XSS (DIM + 8)   // 136 bf16 = 272B row stride

__global__ __launch_bounds__(256) void k_fused(
        const ushort* __restrict__ xb, const ushort* __restrict__ y1r,
        const ushort* __restrict__ y2r, const int* __restrict__ deg,
        const ushort* __restrict__ Wt, const ushort* __restrict__ Wct,
        const float* __restrict__ b_ego, const float* __restrict__ b_h1,
        const float* __restrict__ b_h2, const float* __restrict__ b_cls,
        float* __restrict__ out) {
    __shared__ __align__(16) ushort Xs[32 * XSS];
    __shared__ __align__(16) ushort Hs[32 * XSS];

    int t = threadIdx.x;
    int lane = t & 63, w = t >> 6;
    int q = lane >> 4, l = lane & 15;
    int node0 = blockIdx.x * 32;

    float dvv[2][4];
#pragma unroll
    for (int mt = 0; mt < 2; ++mt) {
        int4 dg = *(const int4*)(deg + node0 + mt * 16 + q * 4);
        dvv[mt][0] = 1.f / (float)max(dg.x, 1);
        dvv[mt][1] = 1.f / (float)max(dg.y, 1);
        dvv[mt][2] = 1.f / (float)max(dg.z, 1);
        dvv[mt][3] = 1.f / (float)max(dg.w, 1);
    }

    f32x4 cout0 = {0.f, 0.f, 0.f, 0.f}, cout1 = {0.f, 0.f, 0.f, 0.f};

    for (int br = 0; br < 3; ++br) {
        const ushort* src = (br == 0) ? xb : (br == 1) ? y1r : y2r;
        const ushort* Wtb = Wt + br * DIM * DIM;
        const float* bias = (br == 0) ? b_ego : (br == 1) ? b_h1 : b_h2;

        __syncthreads();
        {   // stage 32x128 bf16 tile (pure copy)
            int row = t >> 3, col = (t & 7) * 16;
            const ushort* sp = src + ((size_t)(node0 + row) << 7) + col;
            uint4 u0 = *(const uint4*)sp;
            uint4 u1 = *(const uint4*)(sp + 8);
            *(uint4*)(Xs + row * XSS + col) = u0;
            *(uint4*)(Xs + row * XSS + col + 8) = u1;
        }
        __syncthreads();

        short8 afr[2][4];
#pragma unroll
        for (int mt = 0; mt < 2; ++mt)
#pragma unroll
            for (int ks = 0; ks < 4; ++ks)
                afr[mt][ks] = *(const short8*)(Xs + (mt * 16 + l) * XSS + ks * 32 + q * 8);
        short8 bfr[2][4];
#pragma unroll
        for (int nt = 0; nt < 2; ++nt)
#pragma unroll
            for (int ks = 0; ks < 4; ++ks)
                bfr[nt][ks] = *(const short8*)(Wtb + (size_t)(w * 32 + nt * 16 + l) * DIM + ks * 32 + q * 8);

        f32x4 hc[2][2];
        hc[0][0] = hc[0][1] = hc[1][0] = hc[1][1] = (f32x4){0.f, 0.f, 0.f, 0.f};
#pragma unroll
        for (int ks = 0; ks < 4; ++ks)
#pragma unroll
            for (int mt = 0; mt < 2; ++mt)
#pragma unroll
                for (int nt = 0; nt < 2; ++nt)
                    hc[mt][nt] = __builtin_amdgcn_mfma_f32_16x16x32_bf16(
                        afr[mt][ks], bfr[nt][ks], hc[mt][nt], 0, 0, 0);

#pragma unroll
        for (int nt = 0; nt < 2; ++nt) {
            float bv = bias[w * 32 + nt * 16 + l];
#pragma unroll
            for (int mt = 0; mt < 2; ++mt)
#pragma unroll
                for (int r = 0; r < 4; ++r) {
                    float s = (br == 0) ? 1.f
                            : (br == 1) ? dvv[mt][r]
                                        : dvv[mt][r] * dvv[mt][r];
                    float v = hc[mt][nt][r] * s + bv;
                    v = v > 0.f ? v : 0.f;
                    Hs[(mt * 16 + q * 4 + r) * XSS + w * 32 + nt * 16 + l] = f2bf(v);
                }
        }
        __syncthreads();

        short8 ha0 = *(const short8*)(Hs + l * XSS + w * 32 + q * 8);
        short8 ha1 = *(const short8*)(Hs + (16 + l) * XSS + w * 32 + q * 8);
        short8 wc  = *(const short8*)(Wct + (size_t)l * 384 + br * DIM + w * 32 + q * 8);
        cout0 = __builtin_amdgcn_mfma_f32_16x16x32_bf16(ha0, wc, cout0, 0, 0, 0);
        cout1 = __builtin_amdgcn_mfma_f32_16x16x32_bf16(ha1, wc, cout1, 0, 0, 0);
    }

    float* red = (float*)Xs;
#pragma unroll
    for (int r = 0; r < 4; ++r) {
        red[w * 512 + (q * 4 + r) * 16 + l]      = cout0[r];
        red[w * 512 + (16 + q * 4 + r) * 16 + l] = cout1[r];
    }
    __syncthreads();
#pragma unroll
    for (int p = t; p < 512; p += 256) {
        float s = red[p] + red[512 + p] + red[1024 + p] + red[1536 + p];
        out[(size_t)node0 * OUTD + p] = s + b_cls[p & 15];
    }
}

// ---------------- launcher ----------------
static inline size_t align256(size_t v) { return (v + 255) & ~(size_t)255; }

extern "C" void kernel_launch(void* const* d_in, const int* in_sizes, int n_in,
                              void* d_out, int out_size, void* d_ws, size_t ws_size,
                              hipStream_t stream) {
    const float* x      = (const float*)d_in[0];
    const int*   ei     = (const int*)d_in[1];
    const float* W_ego  = (const float*)d_in[2];
    const float* b_ego  = (const float*)d_in[3];
    const float* W_h1   = (const float*)d_in[4];
    const float* b_h1   = (const float*)d_in[5];
    const float* W_h2   = (const float*)d_in[6];
    const float* b_h2   = (const float*)d_in[7];
    const float* W_cls  = (const float*)d_in[8];
    const float* b_cls  = (const float*)d_in[9];
    float* out = (float*)d_out;

    const int* row = ei;
    const int* col = ei + N_EDGES;

    char* p = (char*)d_ws;
    int* deg       = (int*)p;    p += align256((size_t)N_NODES * 4);
    int* offsets   = (int*)p;    p += align256((size_t)(N_NODES + 1) * 4);
    int* hist      = (int*)p;    p += align256((size_t)NBLK * NBUCK * 4);
    int* bbase     = (int*)p;    p += align256((size_t)(NBUCK + 1) * 4);
    uint* packed   = (uint*)p;   p += align256((size_t)N_EDGES * 4);
    int* csr_col   = (int*)p;    p += align256((size_t)N_EDGES * 4);
    ushort* xb     = (ushort*)p; p += align256((size_t)N_NODES * DIM * 2);
    ushort* y1r    = (ushort*)p; p += align256((size_t)N_NODES * DIM * 2);
    ushort* y2r    = (ushort*)p; p += align256((size_t)N_NODES * DIM * 2);
    ushort* Wt     = (ushort*)p; p += align256((size_t)3 * DIM * DIM * 2);
    ushort* Wct    = (ushort*)p; p += align256((size_t)384 * OUTD * 2);

    k_hist<<<NBLK, 256, 0, stream>>>(row, hist);
    k_convert<<<2048, 256, 0, stream>>>((const float4*)x, W_ego, W_h1, W_h2, W_cls,
                                        xb, Wt, Wct);
    k_scanh<<<1, 256, 0, stream>>>(hist, bbase, offsets);
    k_place<<<NBLK, 256, 0, stream>>>(row, col, hist, packed);
    k_build<<<NBUCK, 256, 0, stream>>>(packed, bbase, deg, offsets, csr_col);

    k_spmm<<<N_NODES / 4, 256, 0, stream>>>(xb,  y1r, offsets, csr_col);
    k_spmm<<<N_NODES / 4, 256, 0, stream>>>(y1r, y2r, offsets, csr_col);

    k_fused<<<N_NODES / 32, 256, 0, stream>>>(xb, y1r, y2r, deg, Wt, Wct,
                                              b_ego, b_h1, b_h2, b_cls, out);
}

// Round 9
// 317.598 us; speedup vs baseline: 1.9441x; 1.2001x over previous
//
#include <hip/hip_runtime.h>

#define N_NODES 100000
#define N_EDGES 1600000
#define DIM     128
#define OUTD    16

typedef unsigned int  uint;
typedef unsigned short ushort;
typedef __attribute__((ext_vector_type(8))) short short8;   // 8 bf16 (4 VGPRs)
typedef __attribute__((ext_vector_type(4))) float f32x4;    // MFMA C/D
typedef __attribute__((ext_vector_type(4))) int   i32x4;    // clang vector (nt ok)
typedef __attribute__((ext_vector_type(4))) uint  u32x4;

__device__ __forceinline__ ushort f2bf(float f) {           // RNE fp32->bf16
    uint u = __float_as_uint(f);
    u = u + 0x7fffu + ((u >> 16) & 1u);
    return (ushort)(u >> 16);
}
__device__ __forceinline__ float bflo(uint v) { return __uint_as_float(v << 16); }
__device__ __forceinline__ float bfhi(uint v) { return __uint_as_float(v & 0xffff0000u); }

// ---- bucket decomposition: bucket = row >> 9 (512 rows per bucket) ----
#define RPB    512
#define NBUCK  196                    // ceil(100000/512)
#define NBLK   500                    // hist/place blocks
#define CHUNK4 800                    // int4s per block chunk (3200 edges)
#define BCAP   10240                  // k_build LDS staging capacity

// ---------------- pass 1: per-(block,bucket) histogram, LDS only ----------------
__global__ __launch_bounds__(256) void k_hist(const int* __restrict__ row,
                                              int* __restrict__ hist) {
    __shared__ int h[NBUCK];
    for (int i = threadIdx.x; i < NBUCK; i += 256) h[i] = 0;
    __syncthreads();
    const i32x4* row4 = (const i32x4*)row;
    int base = blockIdx.x * CHUNK4;
    for (int i = threadIdx.x; i < CHUNK4; i += 256) {
        i32x4 r = __builtin_nontemporal_load(row4 + base + i);
        atomicAdd(&h[r.x >> 9], 1);
        atomicAdd(&h[r.y >> 9], 1);
        atomicAdd(&h[r.z >> 9], 1);
        atomicAdd(&h[r.w >> 9], 1);
    }
    __syncthreads();
    for (int i = threadIdx.x; i < NBUCK; i += 256)
        hist[blockIdx.x * NBUCK + i] = h[i];
}

// ---------------- pass 2a: per-bucket parallel column scan (196 blocks) -----------
// hist[k][b] := exclusive prefix over k (no bucket base); btot[b] = column total
__global__ __launch_bounds__(256) void k_scanb(int* __restrict__ hist,
                                               int* __restrict__ btot) {
    __shared__ int psum[256];
    int b = blockIdx.x, t = threadIdx.x;
    int v0 = 0, v1 = 0;
    if (t < NBLK / 2) {
        v0 = hist[(2 * t) * NBUCK + b];
        v1 = hist[(2 * t + 1) * NBUCK + b];
    }
    int s = v0 + v1;
    psum[t] = s;
    __syncthreads();
    for (int off = 1; off < 256; off <<= 1) {
        int a = (t >= off) ? psum[t - off] : 0;
        __syncthreads();
        psum[t] += a;
        __syncthreads();
    }
    int excl = psum[t] - s;
    if (t < NBLK / 2) {
        hist[(2 * t) * NBUCK + b]     = excl;
        hist[(2 * t + 1) * NBUCK + b] = excl + v0;
    }
    if (t == 255) btot[b] = psum[255];
}

// ---------------- pass 2b: tiny scan of bucket totals -> bbase --------------------
__global__ void k_scant(const int* __restrict__ btot, int* __restrict__ bbase,
                        int* __restrict__ offsets) {
    __shared__ int s[256];
    int t = threadIdx.x;
    int v = (t < NBUCK) ? btot[t] : 0;
    s[t] = v;
    __syncthreads();
    for (int off = 1; off < 256; off <<= 1) {
        int a = (t >= off) ? s[t - off] : 0;
        __syncthreads();
        s[t] += a;
        __syncthreads();
    }
    if (t < NBUCK) bbase[t] = s[t] - v;
    if (t == NBUCK - 1) {
        bbase[NBUCK]     = s[t];
        offsets[N_NODES] = s[t];   // == N_EDGES
    }
}

// ---------------- pass 3: place packed (localrow,col) into bucket runs ------------
__global__ __launch_bounds__(256) void k_place(const int* __restrict__ row,
                                               const int* __restrict__ col,
                                               const int* __restrict__ start,
                                               const int* __restrict__ bbase,
                                               uint* __restrict__ packed) {
    __shared__ int cur[NBUCK];
    for (int i = threadIdx.x; i < NBUCK; i += 256)
        cur[i] = start[blockIdx.x * NBUCK + i] + bbase[i];   // base folded here
    __syncthreads();
    const i32x4* row4 = (const i32x4*)row;
    const i32x4* col4 = (const i32x4*)col;
    int base = blockIdx.x * CHUNK4;
    for (int i = threadIdx.x; i < CHUNK4; i += 256) {
        i32x4 r = __builtin_nontemporal_load(row4 + base + i);
        i32x4 c = __builtin_nontemporal_load(col4 + base + i);
        int p;
        p = atomicAdd(&cur[r.x >> 9], 1); packed[p] = ((uint)(r.x & 511) << 17) | (uint)c.x;
        p = atomicAdd(&cur[r.y >> 9], 1); packed[p] = ((uint)(r.y & 511) << 17) | (uint)c.y;
        p = atomicAdd(&cur[r.z >> 9], 1); packed[p] = ((uint)(r.z & 511) << 17) | (uint)c.z;
        p = atomicAdd(&cur[r.w >> 9], 1); packed[p] = ((uint)(r.w & 511) << 17) | (uint)c.w;
    }
}

// ---------------- pass 4: per-bucket CSR build, one WG per bucket -----------------
__global__ __launch_bounds__(256) void k_build(const uint* __restrict__ packed,
                                               const int* __restrict__ bucket_base,
                                               int* __restrict__ deg,
                                               int* __restrict__ offsets,
                                               int* __restrict__ csr_col) {
    __shared__ uint stage[BCAP];               // 40 KB
    __shared__ int hist[RPB];
    __shared__ int loff[RPB];
    __shared__ int psum[256];
    int t = threadIdx.x;
    int b = blockIdx.x;
    int base = bucket_base[b];
    int n    = bucket_base[b + 1] - base;
    int lo   = b * RPB;
    bool lds_ok = (n <= BCAP);

    for (int i = t; i < RPB; i += 256) hist[i] = 0;
    __syncthreads();
    if (lds_ok) {
        for (int i = t; i < n; i += 256) {
            uint pk = packed[base + i];
            stage[i] = pk;
            atomicAdd(&hist[pk >> 17], 1);
        }
    } else {
        for (int i = t; i < n; i += 256) atomicAdd(&hist[packed[base + i] >> 17], 1);
    }
    __syncthreads();

    int a0 = hist[2 * t], a1 = hist[2 * t + 1];
    psum[t] = a0 + a1;
    __syncthreads();
    for (int off = 1; off < 256; off <<= 1) {
        int a = (t >= off) ? psum[t - off] : 0;
        __syncthreads();
        psum[t] += a;
        __syncthreads();
    }
    int excl = psum[t] - (a0 + a1);
    loff[2 * t]     = excl;
    loff[2 * t + 1] = excl + a0;
    __syncthreads();

    for (int i = t; i < RPB; i += 256) {
        int node = lo + i;
        if (node < N_NODES) {
            deg[node]     = hist[i];
            offsets[node] = base + loff[i];
        }
    }
    __syncthreads();

    if (lds_ok) {
        for (int i = t; i < n; i += 256) {
            uint pk = stage[i];
            int p = atomicAdd(&loff[pk >> 17], 1);
            csr_col[base + p] = (int)(pk & 0x1FFFFu);
        }
    } else {
        for (int i = t; i < n; i += 256) {
            uint pk = packed[base + i];
            int p = atomicAdd(&loff[pk >> 17], 1);
            csr_col[base + p] = (int)(pk & 0x1FFFFu);
        }
    }
}

// ---------------- streaming conversions: x->bf16, W transposes ----------------
__global__ __launch_bounds__(256) void k_convert(
        const float4* __restrict__ x4,
        const float* __restrict__ We, const float* __restrict__ W1,
        const float* __restrict__ W2, const float* __restrict__ Wc,
        ushort* __restrict__ xb, ushort* __restrict__ Wt, ushort* __restrict__ Wct) {
    int tid = blockIdx.x * blockDim.x + threadIdx.x;
    int stride = gridDim.x * blockDim.x;
    for (int i = tid; i < N_NODES * DIM / 4; i += stride) {
        float4 v = x4[i];
        ushort4 r;
        r.x = f2bf(v.x); r.y = f2bf(v.y); r.z = f2bf(v.z); r.w = f2bf(v.w);
        *(ushort4*)(xb + (size_t)i * 4) = r;
    }
    for (int i = tid; i < 3 * DIM * DIM; i += stride) {   // Wt[br][n][k] = W[br][k][n]
        int b = i >> 14, r2 = i & (DIM * DIM - 1);
        int k = r2 >> 7, n = r2 & 127;
        const float* W = (b == 0) ? We : (b == 1) ? W1 : W2;
        Wt[b * DIM * DIM + n * DIM + k] = f2bf(W[r2]);
    }
    for (int i = tid; i < 384 * OUTD; i += stride) {      // Wct[o][k] = Wc[k][o]
        int k = i >> 4, o = i & 15;
        Wct[o * 384 + k] = f2bf(Wc[i]);
    }
}

// ---------------- SpMM: quarter-wave 16B gathers, raw sums ----------------
__global__ __launch_bounds__(256) void k_spmm(const ushort* __restrict__ in,
                                              ushort* __restrict__ outp,
                                              const int* __restrict__ offsets,
                                              const int* __restrict__ csr_col) {
    int wid = threadIdx.x >> 6, lane = threadIdx.x & 63;
    int sub = lane >> 4, sl = lane & 15;
    int node = blockIdx.x * 4 + wid;
    int start = __builtin_amdgcn_readfirstlane(offsets[node]);
    int end   = __builtin_amdgcn_readfirstlane(offsets[node + 1]);
    float f0 = 0.f, f1 = 0.f, f2 = 0.f, f3 = 0.f;
    float f4 = 0.f, f5 = 0.f, f6 = 0.f, f7 = 0.f;
    int j = start;
    for (; j + 8 <= end; j += 8) {
        int cA = csr_col[j + sub];
        int cB = csr_col[j + 4 + sub];
        u32x4 a = *(const u32x4*)(in + ((size_t)cA << 7) + sl * 8);
        u32x4 b = *(const u32x4*)(in + ((size_t)cB << 7) + sl * 8);
        f0 += bflo(a.x) + bflo(b.x); f1 += bfhi(a.x) + bfhi(b.x);
        f2 += bflo(a.y) + bflo(b.y); f3 += bfhi(a.y) + bfhi(b.y);
        f4 += bflo(a.z) + bflo(b.z); f5 += bfhi(a.z) + bfhi(b.z);
        f6 += bflo(a.w) + bflo(b.w); f7 += bfhi(a.w) + bfhi(b.w);
    }
    for (; j < end; j += 4) {
        if (j + sub < end) {
            int c = csr_col[j + sub];
            u32x4 a = *(const u32x4*)(in + ((size_t)c << 7) + sl * 8);
            f0 += bflo(a.x); f1 += bfhi(a.x);
            f2 += bflo(a.y); f3 += bfhi(a.y);
            f4 += bflo(a.z); f5 += bfhi(a.z);
            f6 += bflo(a.w); f7 += bfhi(a.w);
        }
    }
    f0 += __shfl_xor(f0, 16, 64); f0 += __shfl_xor(f0, 32, 64);
    f1 += __shfl_xor(f1, 16, 64); f1 += __shfl_xor(f1, 32, 64);
    f2 += __shfl_xor(f2, 16, 64); f2 += __shfl_xor(f2, 32, 64);
    f3 += __shfl_xor(f3, 16, 64); f3 += __shfl_xor(f3, 32, 64);
    f4 += __shfl_xor(f4, 16, 64); f4 += __shfl_xor(f4, 32, 64);
    f5 += __shfl_xor(f5, 16, 64); f5 += __shfl_xor(f5, 32, 64);
    f6 += __shfl_xor(f6, 16, 64); f6 += __shfl_xor(f6, 32, 64);
    f7 += __shfl_xor(f7, 16, 64); f7 += __shfl_xor(f7, 32, 64);
    if (sub == 0) {
        uint o0 = (uint)f2bf(f0) | ((uint)f2bf(f1) << 16);
        uint o1 = (uint)f2bf(f2) | ((uint)f2bf(f3) << 16);
        uint o2 = (uint)f2bf(f4) | ((uint)f2bf(f5) << 16);
        uint o3 = (uint)f2bf(f6) | ((uint)f2bf(f7) << 16);
        u32x4 ov = {o0, o1, o2, o3};
        __builtin_nontemporal_store(ov, (u32x4*)(outp + ((size_t)node << 7) + sl * 8));
    }
}

// ---------------- fused MFMA GEMM x3 (+row-scale norm) + relu + classifier ---------
#define XSS (DIM + 8)   // 136 bf16 = 272B row stride

__global__ __launch_bounds__(256) void k_fused(
        const ushort* __restrict__ xb, const ushort* __restrict__ y1r,
        const ushort* __restrict__ y2r, const int* __restrict__ deg,
        const ushort* __restrict__ Wt, const ushort* __restrict__ Wct,
        const float* __restrict__ b_ego, const float* __restrict__ b_h1,
        const float* __restrict__ b_h2, const float* __restrict__ b_cls,
        float* __restrict__ out) {
    __shared__ __align__(16) ushort Xs[32 * XSS];
    __shared__ __align__(16) ushort Hs[32 * XSS];

    int t = threadIdx.x;
    int lane = t & 63, w = t >> 6;
    int q = lane >> 4, l = lane & 15;
    int node0 = blockIdx.x * 32;

    float dvv[2][4];
#pragma unroll
    for (int mt = 0; mt < 2; ++mt) {
        int4 dg = *(const int4*)(deg + node0 + mt * 16 + q * 4);
        dvv[mt][0] = 1.f / (float)max(dg.x, 1);
        dvv[mt][1] = 1.f / (float)max(dg.y, 1);
        dvv[mt][2] = 1.f / (float)max(dg.z, 1);
        dvv[mt][3] = 1.f / (float)max(dg.w, 1);
    }

    f32x4 cout0 = {0.f, 0.f, 0.f, 0.f}, cout1 = {0.f, 0.f, 0.f, 0.f};

    for (int br = 0; br < 3; ++br) {
        const ushort* src = (br == 0) ? xb : (br == 1) ? y1r : y2r;
        const ushort* Wtb = Wt + br * DIM * DIM;
        const float* bias = (br == 0) ? b_ego : (br == 1) ? b_h1 : b_h2;

        __syncthreads();
        {   // stage 32x128 bf16 tile (pure copy)
            int row = t >> 3, col = (t & 7) * 16;
            const ushort* sp = src + ((size_t)(node0 + row) << 7) + col;
            uint4 u0 = *(const uint4*)sp;
            uint4 u1 = *(const uint4*)(sp + 8);
            *(uint4*)(Xs + row * XSS + col) = u0;
            *(uint4*)(Xs + row * XSS + col + 8) = u1;
        }
        __syncthreads();

        short8 afr[2][4];
#pragma unroll
        for (int mt = 0; mt < 2; ++mt)
#pragma unroll
            for (int ks = 0; ks < 4; ++ks)
                afr[mt][ks] = *(const short8*)(Xs + (mt * 16 + l) * XSS + ks * 32 + q * 8);
        short8 bfr[2][4];
#pragma unroll
        for (int nt = 0; nt < 2; ++nt)
#pragma unroll
            for (int ks = 0; ks < 4; ++ks)
                bfr[nt][ks] = *(const short8*)(Wtb + (size_t)(w * 32 + nt * 16 + l) * DIM + ks * 32 + q * 8);

        f32x4 hc[2][2];
        hc[0][0] = hc[0][1] = hc[1][0] = hc[1][1] = (f32x4){0.f, 0.f, 0.f, 0.f};
#pragma unroll
        for (int ks = 0; ks < 4; ++ks)
#pragma unroll
            for (int mt = 0; mt < 2; ++mt)
#pragma unroll
                for (int nt = 0; nt < 2; ++nt)
                    hc[mt][nt] = __builtin_amdgcn_mfma_f32_16x16x32_bf16(
                        afr[mt][ks], bfr[nt][ks], hc[mt][nt], 0, 0, 0);

#pragma unroll
        for (int nt = 0; nt < 2; ++nt) {
            float bv = bias[w * 32 + nt * 16 + l];
#pragma unroll
            for (int mt = 0; mt < 2; ++mt)
#pragma unroll
                for (int r = 0; r < 4; ++r) {
                    float s = (br == 0) ? 1.f
                            : (br == 1) ? dvv[mt][r]
                                        : dvv[mt][r] * dvv[mt][r];
                    float v = hc[mt][nt][r] * s + bv;
                    v = v > 0.f ? v : 0.f;
                    Hs[(mt * 16 + q * 4 + r) * XSS + w * 32 + nt * 16 + l] = f2bf(v);
                }
        }
        __syncthreads();

        short8 ha0 = *(const short8*)(Hs + l * XSS + w * 32 + q * 8);
        short8 ha1 = *(const short8*)(Hs + (16 + l) * XSS + w * 32 + q * 8);
        short8 wc  = *(const short8*)(Wct + (size_t)l * 384 + br * DIM + w * 32 + q * 8);
        cout0 = __builtin_amdgcn_mfma_f32_16x16x32_bf16(ha0, wc, cout0, 0, 0, 0);
        cout1 = __builtin_amdgcn_mfma_f32_16x16x32_bf16(ha1, wc, cout1, 0, 0, 0);
    }

    float* red = (float*)Xs;
#pragma unroll
    for (int r = 0; r < 4; ++r) {
        red[w * 512 + (q * 4 + r) * 16 + l]      = cout0[r];
        red[w * 512 + (16 + q * 4 + r) * 16 + l] = cout1[r];
    }
    __syncthreads();
#pragma unroll
    for (int p = t; p < 512; p += 256) {
        float s = red[p] + red[512 + p] + red[1024 + p] + red[1536 + p];
        out[(size_t)node0 * OUTD + p] = s + b_cls[p & 15];
    }
}

// ---------------- launcher ----------------
static inline size_t align256(size_t v) { return (v + 255) & ~(size_t)255; }

extern "C" void kernel_launch(void* const* d_in, const int* in_sizes, int n_in,
                              void* d_out, int out_size, void* d_ws, size_t ws_size,
                              hipStream_t stream) {
    const float* x      = (const float*)d_in[0];
    const int*   ei     = (const int*)d_in[1];
    const float* W_ego  = (const float*)d_in[2];
    const float* b_ego  = (const float*)d_in[3];
    const float* W_h1   = (const float*)d_in[4];
    const float* b_h1   = (const float*)d_in[5];
    const float* W_h2   = (const float*)d_in[6];
    const float* b_h2   = (const float*)d_in[7];
    const float* W_cls  = (const float*)d_in[8];
    const float* b_cls  = (const float*)d_in[9];
    float* out = (float*)d_out;

    const int* row = ei;
    const int* col = ei + N_EDGES;

    char* p = (char*)d_ws;
    int* deg       = (int*)p;    p += align256((size_t)N_NODES * 4);
    int* offsets   = (int*)p;    p += align256((size_t)(N_NODES + 1) * 4);
    int* hist      = (int*)p;    p += align256((size_t)NBLK * NBUCK * 4);
    int* bbase     = (int*)p;    p += align256((size_t)(NBUCK + 1) * 4);
    int* btot      = (int*)p;    p += align256((size_t)NBUCK * 4);
    uint* packed   = (uint*)p;   p += align256((size_t)N_EDGES * 4);
    int* csr_col   = (int*)p;    p += align256((size_t)N_EDGES * 4);
    ushort* xb     = (ushort*)p; p += align256((size_t)N_NODES * DIM * 2);
    ushort* y1r    = (ushort*)p; p += align256((size_t)N_NODES * DIM * 2);
    ushort* y2r    = (ushort*)p; p += align256((size_t)N_NODES * DIM * 2);
    ushort* Wt     = (ushort*)p; p += align256((size_t)3 * DIM * DIM * 2);
    ushort* Wct    = (ushort*)p; p += align256((size_t)384 * OUTD * 2);

    k_hist<<<NBLK, 256, 0, stream>>>(row, hist);
    k_convert<<<2048, 256, 0, stream>>>((const float4*)x, W_ego, W_h1, W_h2, W_cls,
                                        xb, Wt, Wct);
    k_scanb<<<NBUCK, 256, 0, stream>>>(hist, btot);
    k_scant<<<1, 256, 0, stream>>>(btot, bbase, offsets);
    k_place<<<NBLK, 256, 0, stream>>>(row, col, hist, bbase, packed);
    k_build<<<NBUCK, 256, 0, stream>>>(packed, bbase, deg, offsets, csr_col);

    k_spmm<<<N_NODES / 4, 256, 0, stream>>>(xb,  y1r, offsets, csr_col);
    k_spmm<<<N_NODES / 4, 256, 0, stream>>>(y1r, y2r, offsets, csr_col);

    k_fused<<<N_NODES / 32, 256, 0, stream>>>(xb, y1r, y2r, deg, Wt, Wct,
                                              b_ego, b_h1, b_h2, b_cls, out);
}

// Round 10
// 311.187 us; speedup vs baseline: 1.9841x; 1.0206x over previous
//
#include <hip/hip_runtime.h>

#define N_NODES 100000
#define N_EDGES 1600000
#define DIM     128
#define OUTD    16

typedef unsigned int  uint;
typedef unsigned short ushort;
typedef __attribute__((ext_vector_type(8))) short short8;   // 8 bf16 (4 VGPRs)
typedef __attribute__((ext_vector_type(4))) float f32x4;    // MFMA C/D
typedef __attribute__((ext_vector_type(4))) int   i32x4;    // clang vector (nt ok)
typedef __attribute__((ext_vector_type(4), aligned(4))) int i32x4u;  // 4B-aligned dwordx4
typedef __attribute__((ext_vector_type(4))) uint  u32x4;

__device__ __forceinline__ ushort f2bf(float f) {           // RNE fp32->bf16
    uint u = __float_as_uint(f);
    u = u + 0x7fffu + ((u >> 16) & 1u);
    return (ushort)(u >> 16);
}
__device__ __forceinline__ float bflo(uint v) { return __uint_as_float(v << 16); }
__device__ __forceinline__ float bfhi(uint v) { return __uint_as_float(v & 0xffff0000u); }

// ---- bucket decomposition: bucket = row >> 9 (512 rows per bucket) ----
#define RPB    512
#define NBUCK  196                    // ceil(100000/512)
#define NBLK   500                    // hist/place blocks
#define CHUNK4 800                    // int4s per block chunk (3200 edges)
#define BCAP   10240                  // k_build LDS staging capacity

// ---------------- fused: per-block histogram (blocks<NBLK) + conversions ----------
__global__ __launch_bounds__(256) void k_convert(
        const float4* __restrict__ x4, const int* __restrict__ row,
        int* __restrict__ hist,
        const float* __restrict__ We, const float* __restrict__ W1,
        const float* __restrict__ W2, const float* __restrict__ Wc,
        ushort* __restrict__ xb, ushort* __restrict__ Wt, ushort* __restrict__ Wct) {
    __shared__ int h[NBUCK];
    if (blockIdx.x < NBLK) {          // block-uniform branch: barriers legal
        for (int i = threadIdx.x; i < NBUCK; i += 256) h[i] = 0;
        __syncthreads();
        const i32x4* row4 = (const i32x4*)row;
        int base = blockIdx.x * CHUNK4;
        for (int i = threadIdx.x; i < CHUNK4; i += 256) {
            i32x4 r = __builtin_nontemporal_load(row4 + base + i);
            atomicAdd(&h[r.x >> 9], 1);
            atomicAdd(&h[r.y >> 9], 1);
            atomicAdd(&h[r.z >> 9], 1);
            atomicAdd(&h[r.w >> 9], 1);
        }
        __syncthreads();
        for (int i = threadIdx.x; i < NBUCK; i += 256)
            hist[blockIdx.x * NBUCK + i] = h[i];
    }
    int tid = blockIdx.x * blockDim.x + threadIdx.x;
    int stride = gridDim.x * blockDim.x;
    for (int i = tid; i < N_NODES * DIM / 4; i += stride) {
        float4 v = x4[i];
        ushort4 r;
        r.x = f2bf(v.x); r.y = f2bf(v.y); r.z = f2bf(v.z); r.w = f2bf(v.w);
        *(ushort4*)(xb + (size_t)i * 4) = r;
    }
    for (int i = tid; i < 3 * DIM * DIM; i += stride) {   // Wt[br][n][k] = W[br][k][n]
        int b = i >> 14, r2 = i & (DIM * DIM - 1);
        int k = r2 >> 7, n = r2 & 127;
        const float* W = (b == 0) ? We : (b == 1) ? W1 : W2;
        Wt[b * DIM * DIM + n * DIM + k] = f2bf(W[r2]);
    }
    for (int i = tid; i < 384 * OUTD; i += stride) {      // Wct[o][k] = Wc[k][o]
        int k = i >> 4, o = i & 15;
        Wct[o * 384 + k] = f2bf(Wc[i]);
    }
}

// ---------------- pass 2a: per-bucket parallel column scan (196 blocks) -----------
__global__ __launch_bounds__(256) void k_scanb(int* __restrict__ hist,
                                               int* __restrict__ btot) {
    __shared__ int psum[256];
    int b = blockIdx.x, t = threadIdx.x;
    int v0 = 0, v1 = 0;
    if (t < NBLK / 2) {
        v0 = hist[(2 * t) * NBUCK + b];
        v1 = hist[(2 * t + 1) * NBUCK + b];
    }
    int s = v0 + v1;
    psum[t] = s;
    __syncthreads();
    for (int off = 1; off < 256; off <<= 1) {
        int a = (t >= off) ? psum[t - off] : 0;
        __syncthreads();
        psum[t] += a;
        __syncthreads();
    }
    int excl = psum[t] - s;
    if (t < NBLK / 2) {
        hist[(2 * t) * NBUCK + b]     = excl;
        hist[(2 * t + 1) * NBUCK + b] = excl + v0;
    }
    if (t == 255) btot[b] = psum[255];
}

// ---------------- pass 2b: tiny scan of bucket totals -> bbase --------------------
__global__ void k_scant(const int* __restrict__ btot, int* __restrict__ bbase,
                        int* __restrict__ offsets) {
    __shared__ int s[256];
    int t = threadIdx.x;
    int v = (t < NBUCK) ? btot[t] : 0;
    s[t] = v;
    __syncthreads();
    for (int off = 1; off < 256; off <<= 1) {
        int a = (t >= off) ? s[t - off] : 0;
        __syncthreads();
        s[t] += a;
        __syncthreads();
    }
    if (t < NBUCK) bbase[t] = s[t] - v;
    if (t == NBUCK - 1) {
        bbase[NBUCK]     = s[t];
        offsets[N_NODES] = s[t];   // == N_EDGES
    }
}

// ---------------- pass 3: place packed (localrow,col) into bucket runs ------------
__global__ __launch_bounds__(256) void k_place(const int* __restrict__ row,
                                               const int* __restrict__ col,
                                               const int* __restrict__ start,
                                               const int* __restrict__ bbase,
                                               uint* __restrict__ packed) {
    __shared__ int cur[NBUCK];
    for (int i = threadIdx.x; i < NBUCK; i += 256)
        cur[i] = start[blockIdx.x * NBUCK + i] + bbase[i];
    __syncthreads();
    const i32x4* row4 = (const i32x4*)row;
    const i32x4* col4 = (const i32x4*)col;
    int base = blockIdx.x * CHUNK4;
    for (int i = threadIdx.x; i < CHUNK4; i += 256) {
        i32x4 r = __builtin_nontemporal_load(row4 + base + i);
        i32x4 c = __builtin_nontemporal_load(col4 + base + i);
        int p;
        p = atomicAdd(&cur[r.x >> 9], 1); packed[p] = ((uint)(r.x & 511) << 17) | (uint)c.x;
        p = atomicAdd(&cur[r.y >> 9], 1); packed[p] = ((uint)(r.y & 511) << 17) | (uint)c.y;
        p = atomicAdd(&cur[r.z >> 9], 1); packed[p] = ((uint)(r.z & 511) << 17) | (uint)c.z;
        p = atomicAdd(&cur[r.w >> 9], 1); packed[p] = ((uint)(r.w & 511) << 17) | (uint)c.w;
    }
}

// ---------------- pass 4: per-bucket CSR build, one WG per bucket -----------------
__global__ __launch_bounds__(256) void k_build(const uint* __restrict__ packed,
                                               const int* __restrict__ bucket_base,
                                               int* __restrict__ deg,
                                               int* __restrict__ offsets,
                                               int* __restrict__ csr_col) {
    __shared__ uint stage[BCAP];               // 40 KB
    __shared__ int hist[RPB];
    __shared__ int loff[RPB];
    __shared__ int psum[256];
    int t = threadIdx.x;
    int b = blockIdx.x;
    int base = bucket_base[b];
    int n    = bucket_base[b + 1] - base;
    int lo   = b * RPB;
    bool lds_ok = (n <= BCAP);

    for (int i = t; i < RPB; i += 256) hist[i] = 0;
    __syncthreads();
    if (lds_ok) {
        for (int i = t; i < n; i += 256) {
            uint pk = packed[base + i];
            stage[i] = pk;
            atomicAdd(&hist[pk >> 17], 1);
        }
    } else {
        for (int i = t; i < n; i += 256) atomicAdd(&hist[packed[base + i] >> 17], 1);
    }
    __syncthreads();

    int a0 = hist[2 * t], a1 = hist[2 * t + 1];
    psum[t] = a0 + a1;
    __syncthreads();
    for (int off = 1; off < 256; off <<= 1) {
        int a = (t >= off) ? psum[t - off] : 0;
        __syncthreads();
        psum[t] += a;
        __syncthreads();
    }
    int excl = psum[t] - (a0 + a1);
    loff[2 * t]     = excl;
    loff[2 * t + 1] = excl + a0;
    __syncthreads();

    for (int i = t; i < RPB; i += 256) {
        int node = lo + i;
        if (node < N_NODES) {
            deg[node]     = hist[i];
            offsets[node] = base + loff[i];
        }
    }
    __syncthreads();

    if (lds_ok) {
        for (int i = t; i < n; i += 256) {
            uint pk = stage[i];
            int p = atomicAdd(&loff[pk >> 17], 1);
            csr_col[base + p] = (int)(pk & 0x1FFFFu);
        }
    } else {
        for (int i = t; i < n; i += 256) {
            uint pk = packed[base + i];
            int p = atomicAdd(&loff[pk >> 17], 1);
            csr_col[base + p] = (int)(pk & 0x1FFFFu);
        }
    }
}

// ---------------- SpMM: 16-edge main loop, 4 gathers in flight per lane -----------
// sub s owns edges j+4s..j+4s+3 via ONE dwordx4 index load (4B-aligned OK on gfx9+)
__global__ __launch_bounds__(256) void k_spmm(const ushort* __restrict__ in,
                                              ushort* __restrict__ outp,
                                              const int* __restrict__ offsets,
                                              const int* __restrict__ csr_col) {
    int wid = threadIdx.x >> 6, lane = threadIdx.x & 63;
    int sub = lane >> 4, sl = lane & 15;
    int node = blockIdx.x * 4 + wid;
    int start = __builtin_amdgcn_readfirstlane(offsets[node]);
    int end   = __builtin_amdgcn_readfirstlane(offsets[node + 1]);
    float f0 = 0.f, f1 = 0.f, f2 = 0.f, f3 = 0.f;
    float f4 = 0.f, f5 = 0.f, f6 = 0.f, f7 = 0.f;
    int j = start;
    for (; j + 16 <= end; j += 16) {
        i32x4u c = *(const i32x4u*)(csr_col + j + 4 * sub);
        u32x4 a = *(const u32x4*)(in + ((size_t)c.x << 7) + sl * 8);
        u32x4 b = *(const u32x4*)(in + ((size_t)c.y << 7) + sl * 8);
        u32x4 d = *(const u32x4*)(in + ((size_t)c.z << 7) + sl * 8);
        u32x4 e = *(const u32x4*)(in + ((size_t)c.w << 7) + sl * 8);
        f0 += bflo(a.x) + bflo(b.x) + bflo(d.x) + bflo(e.x);
        f1 += bfhi(a.x) + bfhi(b.x) + bfhi(d.x) + bfhi(e.x);
        f2 += bflo(a.y) + bflo(b.y) + bflo(d.y) + bflo(e.y);
        f3 += bfhi(a.y) + bfhi(b.y) + bfhi(d.y) + bfhi(e.y);
        f4 += bflo(a.z) + bflo(b.z) + bflo(d.z) + bflo(e.z);
        f5 += bfhi(a.z) + bfhi(b.z) + bfhi(d.z) + bfhi(e.z);
        f6 += bflo(a.w) + bflo(b.w) + bflo(d.w) + bflo(e.w);
        f7 += bfhi(a.w) + bfhi(b.w) + bfhi(d.w) + bfhi(e.w);
    }
    for (; j + 8 <= end; j += 8) {
        int cA = csr_col[j + sub];
        int cB = csr_col[j + 4 + sub];
        u32x4 a = *(const u32x4*)(in + ((size_t)cA << 7) + sl * 8);
        u32x4 b = *(const u32x4*)(in + ((size_t)cB << 7) + sl * 8);
        f0 += bflo(a.x) + bflo(b.x); f1 += bfhi(a.x) + bfhi(b.x);
        f2 += bflo(a.y) + bflo(b.y); f3 += bfhi(a.y) + bfhi(b.y);
        f4 += bflo(a.z) + bflo(b.z); f5 += bfhi(a.z) + bfhi(b.z);
        f6 += bflo(a.w) + bflo(b.w); f7 += bfhi(a.w) + bfhi(b.w);
    }
    for (; j < end; j += 4) {
        if (j + sub < end) {
            int c = csr_col[j + sub];
            u32x4 a = *(const u32x4*)(in + ((size_t)c << 7) + sl * 8);
            f0 += bflo(a.x); f1 += bfhi(a.x);
            f2 += bflo(a.y); f3 += bfhi(a.y);
            f4 += bflo(a.z); f5 += bfhi(a.z);
            f6 += bflo(a.w); f7 += bfhi(a.w);
        }
    }
    f0 += __shfl_xor(f0, 16, 64); f0 += __shfl_xor(f0, 32, 64);
    f1 += __shfl_xor(f1, 16, 64); f1 += __shfl_xor(f1, 32, 64);
    f2 += __shfl_xor(f2, 16, 64); f2 += __shfl_xor(f2, 32, 64);
    f3 += __shfl_xor(f3, 16, 64); f3 += __shfl_xor(f3, 32, 64);
    f4 += __shfl_xor(f4, 16, 64); f4 += __shfl_xor(f4, 32, 64);
    f5 += __shfl_xor(f5, 16, 64); f5 += __shfl_xor(f5, 32, 64);
    f6 += __shfl_xor(f6, 16, 64); f6 += __shfl_xor(f6, 32, 64);
    f7 += __shfl_xor(f7, 16, 64); f7 += __shfl_xor(f7, 32, 64);
    if (sub == 0) {
        uint o0 = (uint)f2bf(f0) | ((uint)f2bf(f1) << 16);
        uint o1 = (uint)f2bf(f2) | ((uint)f2bf(f3) << 16);
        uint o2 = (uint)f2bf(f4) | ((uint)f2bf(f5) << 16);
        uint o3 = (uint)f2bf(f6) | ((uint)f2bf(f7) << 16);
        u32x4 ov = {o0, o1, o2, o3};
        __builtin_nontemporal_store(ov, (u32x4*)(outp + ((size_t)node << 7) + sl * 8));
    }
}

// ---------------- fused MFMA GEMM x3 (+row-scale norm) + relu + classifier ---------
#define XSS (DIM + 8)   // 136 bf16 = 272B row stride

__global__ __launch_bounds__(256) void k_fused(
        const ushort* __restrict__ xb, const ushort* __restrict__ y1r,
        const ushort* __restrict__ y2r, const int* __restrict__ deg,
        const ushort* __restrict__ Wt, const ushort* __restrict__ Wct,
        const float* __restrict__ b_ego, const float* __restrict__ b_h1,
        const float* __restrict__ b_h2, const float* __restrict__ b_cls,
        float* __restrict__ out) {
    __shared__ __align__(16) ushort Xs[32 * XSS];
    __shared__ __align__(16) ushort Hs[32 * XSS];

    int t = threadIdx.x;
    int lane = t & 63, w = t >> 6;
    int q = lane >> 4, l = lane & 15;
    int node0 = blockIdx.x * 32;

    float dvv[2][4];
#pragma unroll
    for (int mt = 0; mt < 2; ++mt) {
        int4 dg = *(const int4*)(deg + node0 + mt * 16 + q * 4);
        dvv[mt][0] = 1.f / (float)max(dg.x, 1);
        dvv[mt][1] = 1.f / (float)max(dg.y, 1);
        dvv[mt][2] = 1.f / (float)max(dg.z, 1);
        dvv[mt][3] = 1.f / (float)max(dg.w, 1);
    }

    f32x4 cout0 = {0.f, 0.f, 0.f, 0.f}, cout1 = {0.f, 0.f, 0.f, 0.f};

    for (int br = 0; br < 3; ++br) {
        const ushort* src = (br == 0) ? xb : (br == 1) ? y1r : y2r;
        const ushort* Wtb = Wt + br * DIM * DIM;
        const float* bias = (br == 0) ? b_ego : (br == 1) ? b_h1 : b_h2;

        __syncthreads();
        {   // stage 32x128 bf16 tile (pure copy)
            int row = t >> 3, col = (t & 7) * 16;
            const ushort* sp = src + ((size_t)(node0 + row) << 7) + col;
            uint4 u0 = *(const uint4*)sp;
            uint4 u1 = *(const uint4*)(sp + 8);
            *(uint4*)(Xs + row * XSS + col) = u0;
            *(uint4*)(Xs + row * XSS + col + 8) = u1;
        }
        __syncthreads();

        short8 afr[2][4];
#pragma unroll
        for (int mt = 0; mt < 2; ++mt)
#pragma unroll
            for (int ks = 0; ks < 4; ++ks)
                afr[mt][ks] = *(const short8*)(Xs + (mt * 16 + l) * XSS + ks * 32 + q * 8);
        short8 bfr[2][4];
#pragma unroll
        for (int nt = 0; nt < 2; ++nt)
#pragma unroll
            for (int ks = 0; ks < 4; ++ks)
                bfr[nt][ks] = *(const short8*)(Wtb + (size_t)(w * 32 + nt * 16 + l) * DIM + ks * 32 + q * 8);

        f32x4 hc[2][2];
        hc[0][0] = hc[0][1] = hc[1][0] = hc[1][1] = (f32x4){0.f, 0.f, 0.f, 0.f};
#pragma unroll
        for (int ks = 0; ks < 4; ++ks)
#pragma unroll
            for (int mt = 0; mt < 2; ++mt)
#pragma unroll
                for (int nt = 0; nt < 2; ++nt)
                    hc[mt][nt] = __builtin_amdgcn_mfma_f32_16x16x32_bf16(
                        afr[mt][ks], bfr[nt][ks], hc[mt][nt], 0, 0, 0);

#pragma unroll
        for (int nt = 0; nt < 2; ++nt) {
            float bv = bias[w * 32 + nt * 16 + l];
#pragma unroll
            for (int mt = 0; mt < 2; ++mt)
#pragma unroll
                for (int r = 0; r < 4; ++r) {
                    float s = (br == 0) ? 1.f
                            : (br == 1) ? dvv[mt][r]
                                        : dvv[mt][r] * dvv[mt][r];
                    float v = hc[mt][nt][r] * s + bv;
                    v = v > 0.f ? v : 0.f;
                    Hs[(mt * 16 + q * 4 + r) * XSS + w * 32 + nt * 16 + l] = f2bf(v);
                }
        }
        __syncthreads();

        short8 ha0 = *(const short8*)(Hs + l * XSS + w * 32 + q * 8);
        short8 ha1 = *(const short8*)(Hs + (16 + l) * XSS + w * 32 + q * 8);
        short8 wc  = *(const short8*)(Wct + (size_t)l * 384 + br * DIM + w * 32 + q * 8);
        cout0 = __builtin_amdgcn_mfma_f32_16x16x32_bf16(ha0, wc, cout0, 0, 0, 0);
        cout1 = __builtin_amdgcn_mfma_f32_16x16x32_bf16(ha1, wc, cout1, 0, 0, 0);
    }

    float* red = (float*)Xs;
#pragma unroll
    for (int r = 0; r < 4; ++r) {
        red[w * 512 + (q * 4 + r) * 16 + l]      = cout0[r];
        red[w * 512 + (16 + q * 4 + r) * 16 + l] = cout1[r];
    }
    __syncthreads();
#pragma unroll
    for (int p = t; p < 512; p += 256) {
        float s = red[p] + red[512 + p] + red[1024 + p] + red[1536 + p];
        out[(size_t)node0 * OUTD + p] = s + b_cls[p & 15];
    }
}

// ---------------- launcher ----------------
static inline size_t align256(size_t v) { return (v + 255) & ~(size_t)255; }

extern "C" void kernel_launch(void* const* d_in, const int* in_sizes, int n_in,
                              void* d_out, int out_size, void* d_ws, size_t ws_size,
                              hipStream_t stream) {
    const float* x      = (const float*)d_in[0];
    const int*   ei     = (const int*)d_in[1];
    const float* W_ego  = (const float*)d_in[2];
    const float* b_ego  = (const float*)d_in[3];
    const float* W_h1   = (const float*)d_in[4];
    const float* b_h1   = (const float*)d_in[5];
    const float* W_h2   = (const float*)d_in[6];
    const float* b_h2   = (const float*)d_in[7];
    const float* W_cls  = (const float*)d_in[8];
    const float* b_cls  = (const float*)d_in[9];
    float* out = (float*)d_out;

    const int* row = ei;
    const int* col = ei + N_EDGES;

    char* p = (char*)d_ws;
    int* deg       = (int*)p;    p += align256((size_t)N_NODES * 4);
    int* offsets   = (int*)p;    p += align256((size_t)(N_NODES + 1) * 4);
    int* hist      = (int*)p;    p += align256((size_t)NBLK * NBUCK * 4);
    int* bbase     = (int*)p;    p += align256((size_t)(NBUCK + 1) * 4);
    int* btot      = (int*)p;    p += align256((size_t)NBUCK * 4);
    uint* packed   = (uint*)p;   p += align256((size_t)N_EDGES * 4);
    int* csr_col   = (int*)p;    p += align256((size_t)N_EDGES * 4);
    ushort* xb     = (ushort*)p; p += align256((size_t)N_NODES * DIM * 2);
    ushort* y1r    = (ushort*)p; p += align256((size_t)N_NODES * DIM * 2);
    ushort* y2r    = (ushort*)p; p += align256((size_t)N_NODES * DIM * 2);
    ushort* Wt     = (ushort*)p; p += align256((size_t)3 * DIM * DIM * 2);
    ushort* Wct    = (ushort*)p; p += align256((size_t)384 * OUTD * 2);

    k_convert<<<2048, 256, 0, stream>>>((const float4*)x, row, hist,
                                        W_ego, W_h1, W_h2, W_cls, xb, Wt, Wct);
    k_scanb<<<NBUCK, 256, 0, stream>>>(hist, btot);
    k_scant<<<1, 256, 0, stream>>>(btot, bbase, offsets);
    k_place<<<NBLK, 256, 0, stream>>>(row, col, hist, bbase, packed);
    k_build<<<NBUCK, 256, 0, stream>>>(packed, bbase, deg, offsets, csr_col);

    k_spmm<<<N_NODES / 4, 256, 0, stream>>>(xb,  y1r, offsets, csr_col);
    k_spmm<<<N_NODES / 4, 256, 0, stream>>>(y1r, y2r, offsets, csr_col);

    k_fused<<<N_NODES / 32, 256, 0, stream>>>(xb, y1r, y2r, deg, Wt, Wct,
                                              b_ego, b_h1, b_h2, b_cls, out);
}